// Round 1
// baseline (384.676 us; speedup 1.0000x reference)
//
#include <hip/hip_runtime.h>

#define T_ 16
#define N_ 128
#define F_ 128

__device__ __forceinline__ float fast_tanh(float x) {
    // tanh(x) = 1 - 2/(exp(2x)+1); v_exp_f32 + native rcp-div. Handles +-inf correctly.
    float e = __expf(2.0f * x);
    return 1.0f - __fdividef(2.0f, e + 1.0f);
}

__device__ __forceinline__ float lrelu(float v) {
    return v >= 0.0f ? v : 0.01f * v;
}

// ---------------- prep: transpose node_w for coalesced GEMM loads + zero BN accumulators ----------------
__global__ void wprep(const float* __restrict__ W, float* __restrict__ WT,
                      float* __restrict__ bn) {
    int l = blockIdx.y;
    int idx = blockIdx.x * 256 + threadIdx.x;   // 0..16383
    int g = idx >> 7, f = idx & 127;
    WT[l * 16384 + f * 128 + g] = W[l * 16384 + idx];
    if (l == 0 && blockIdx.x == 0) {
        bn[threadIdx.x] = 0.0f;          // layer 0 sums
        bn[256 + threadIdx.x] = 0.0f;    // layer 1 sums
    }
}

// ---------------- sim_cal (optionally fused with BN-apply + lrelu + x_next writeback) ----------------
// grid (T, 8), block 128. Each block: full X[t] in LDS, computes 16 n-rows x 128 m-cols.
// BN=true: input is pre-BN y; apply (y-mu)*inv*gamma+beta then lrelu on load; ch==0 writes x_next.
template<bool BN>
__global__ __launch_bounds__(128) void sim_k(const float* __restrict__ x,
                                             const float* __restrict__ bnS,
                                             const float* __restrict__ gamma,
                                             const float* __restrict__ beta,
                                             float* __restrict__ out,
                                             float* __restrict__ xout) {
    __shared__ float Xs[128][132];   // pad 132: 16B-aligned rows
    __shared__ float nrm[128];
    int t = blockIdx.x, ch = blockIdx.y;
    int m = threadIdx.x;
    const float* xt = x + (size_t)t * (N_ * F_);
    int fg = (m & 31) * 4, ko = m >> 5;

    float4 sc, sh;   // y*sc + sh == (y-mu)*inv*gamma + beta
    if constexpr (BN) {
        float4 s1 = *(const float4*)(bnS + fg);
        float4 s2 = *(const float4*)(bnS + 128 + fg);
        float4 ga = *(const float4*)(gamma + fg);
        float4 be = *(const float4*)(beta + fg);
        const float inv_n = 1.0f / 2048.0f;
        float mx = s1.x * inv_n, my = s1.y * inv_n, mz = s1.z * inv_n, mw = s1.w * inv_n;
        sc.x = rsqrtf(s2.x * inv_n - mx * mx + 1e-5f) * ga.x;
        sc.y = rsqrtf(s2.y * inv_n - my * my + 1e-5f) * ga.y;
        sc.z = rsqrtf(s2.z * inv_n - mz * mz + 1e-5f) * ga.z;
        sc.w = rsqrtf(s2.w * inv_n - mw * mw + 1e-5f) * ga.w;
        sh.x = be.x - mx * sc.x;
        sh.y = be.y - my * sc.y;
        sh.z = be.z - mz * sc.z;
        sh.w = be.w - mw * sc.w;
    }

    // cooperative load, coalesced float4; BN+lrelu applied in-flight
    bool wout = false;
    if constexpr (BN) wout = (ch == 0) && (xout != nullptr);
    for (int kb = 0; kb < 128; kb += 4) {
        int k = kb + ko;
        float4 v = *(const float4*)(xt + k * 128 + fg);
        if constexpr (BN) {
            v.x = lrelu(fmaf(v.x, sc.x, sh.x));
            v.y = lrelu(fmaf(v.y, sc.y, sh.y));
            v.z = lrelu(fmaf(v.z, sc.z, sh.z));
            v.w = lrelu(fmaf(v.w, sc.w, sh.w));
            if (wout) *(float4*)(xout + (size_t)t * 16384 + k * 128 + fg) = v;
        }
        *(float4*)&Xs[k][fg] = v;
    }
    __syncthreads();

    // norm of row m
    float s = 0.0f;
    #pragma unroll 8
    for (int f = 0; f < 128; f += 4) {
        float4 v = *(float4*)&Xs[m][f];
        s += v.x * v.x + v.y * v.y + v.z * v.z + v.w * v.w;
    }
    nrm[m] = sqrtf(s);
    __syncthreads();

    float acc[16];
    #pragma unroll
    for (int r = 0; r < 16; ++r) acc[r] = 0.0f;

    for (int fc = 0; fc < 128; fc += 32) {
        float xm[32];
        #pragma unroll
        for (int f = 0; f < 32; f += 4) {
            float4 v = *(float4*)&Xs[m][fc + f];
            xm[f] = v.x; xm[f + 1] = v.y; xm[f + 2] = v.z; xm[f + 3] = v.w;
        }
        #pragma unroll
        for (int r = 0; r < 16; ++r) {
            int n = ch * 16 + r;
            #pragma unroll
            for (int f = 0; f < 32; f += 4) {
                float4 v = *(float4*)&Xs[n][fc + f];
                acc[r] = fmaf(xm[f], v.x,
                         fmaf(xm[f + 1], v.y,
                         fmaf(xm[f + 2], v.z,
                         fmaf(xm[f + 3], v.w, acc[r]))));
            }
        }
    }

    float nm = nrm[m];
    size_t ob = (size_t)t * 2 * 16384;
    #pragma unroll
    for (int r = 0; r < 16; ++r) {
        int n = ch * 16 + r;
        float denom = nrm[n] * nm + 1e-6f;
        float sim = __fdividef(acc[r], denom);
        float s0 = fminf(fmaxf(sim, 0.0f), 1.0f);
        float s1 = fminf(fmaxf(1.0f - sim, 0.0f), 1.0f);
        out[ob + (size_t)n * 128 + m] = s0;
        out[ob + 16384 + (size_t)n * 128 + m] = s1;
    }
}

// ---------------- fused layer: edge tanh + aggregate + node combine + GEMM + BN partials ----------------
// grid 2048 (= t*128+i), block 256 (4 waves -> 8 blocks/CU = 32 waves/CU).
// Phase A: threads (jl 0..7, fg 0..31) stream E row i, accumulate tanh sum over j.
// Phase B: 8-way LDS reduce -> aggr[128].
// Phase C: h[g] = lrelu(c0*x_i[g] + c1*aggr[g]).
// Phase D: y[g] = sum_f h[f]*WT[f][g], 2 threads/g (f-halves); write y + atomic BN sums.
template<int LAYER>
__global__ __launch_bounds__(256) void layer_fused(const float* __restrict__ x0,
                                                   const float* __restrict__ x1,
                                                   const float* __restrict__ E,
                                                   const float* __restrict__ ew,
                                                   const float* __restrict__ eb,
                                                   const float* __restrict__ cw,
                                                   const float* __restrict__ WT,
                                                   float* __restrict__ y_out,
                                                   float* __restrict__ bnL) {
    __shared__ float4 red[256];
    __shared__ __align__(16) float aggr[128];
    __shared__ float hs[128];
    __shared__ float yred[128];

    int ti = blockIdx.x;
    int t = ti >> 7, i = ti & 127;
    int tid = threadIdx.x;
    int jl = tid >> 5, fg = tid & 31;

    const float4* xt0 = (const float4*)(x0 + (size_t)t * 16384);
    const float4* xt1 = (const float4*)(x1 + (size_t)t * 16384);
    const float4* Ei  = (const float4*)(E + (size_t)ti * 16384);

    float w00 = ew[0], w01 = ew[1], w02 = ew[2], b0 = eb[0];
    float w10 = 0.f, w11 = 0.f, w12 = 0.f, b1 = 0.f;
    if constexpr (LAYER == 1) { w10 = ew[3]; w11 = ew[4]; w12 = ew[5]; b1 = eb[1]; }

    float4 xi0 = xt0[i * 32 + fg];
    float4 xi1 = xi0;
    if constexpr (LAYER == 1) xi1 = xt1[i * 32 + fg];

    float ax = 0.f, ay = 0.f, az = 0.f, aw = 0.f;
    if constexpr (LAYER == 0) {
        #pragma unroll 4
        for (int jb = 0; jb < 128; jb += 8) {
            int j = jb + jl;
            float4 ev  = Ei[j * 32 + fg];
            float4 xj0 = xt0[j * 32 + fg];
            if (j != i) {
                ax += fast_tanh(fmaf(w00, xi0.x, fmaf(w01, xi0.x - xj0.x, fmaf(w02, ev.x, b0))));
                ay += fast_tanh(fmaf(w00, xi0.y, fmaf(w01, xi0.y - xj0.y, fmaf(w02, ev.y, b0))));
                az += fast_tanh(fmaf(w00, xi0.z, fmaf(w01, xi0.z - xj0.z, fmaf(w02, ev.z, b0))));
                aw += fast_tanh(fmaf(w00, xi0.w, fmaf(w01, xi0.w - xj0.w, fmaf(w02, ev.w, b0))));
            }
        }
    } else {
        #pragma unroll 2
        for (int jb = 0; jb < 128; jb += 8) {
            int j = jb + jl;
            float4 ev  = Ei[j * 32 + fg];
            float4 xj0 = xt0[j * 32 + fg];
            float4 xj1 = xt1[j * 32 + fg];
            if (j != i) {
                float e0x = fast_tanh(fmaf(w00, xi0.x, fmaf(w01, xi0.x - xj0.x, fmaf(w02, ev.x, b0))));
                float e0y = fast_tanh(fmaf(w00, xi0.y, fmaf(w01, xi0.y - xj0.y, fmaf(w02, ev.y, b0))));
                float e0z = fast_tanh(fmaf(w00, xi0.z, fmaf(w01, xi0.z - xj0.z, fmaf(w02, ev.z, b0))));
                float e0w = fast_tanh(fmaf(w00, xi0.w, fmaf(w01, xi0.w - xj0.w, fmaf(w02, ev.w, b0))));
                ax += fast_tanh(fmaf(w10, xi1.x, fmaf(w11, xi1.x - xj1.x, fmaf(w12, e0x, b1))));
                ay += fast_tanh(fmaf(w10, xi1.y, fmaf(w11, xi1.y - xj1.y, fmaf(w12, e0y, b1))));
                az += fast_tanh(fmaf(w10, xi1.z, fmaf(w11, xi1.z - xj1.z, fmaf(w12, e0z, b1))));
                aw += fast_tanh(fmaf(w10, xi1.w, fmaf(w11, xi1.w - xj1.w, fmaf(w12, e0w, b1))));
            }
        }
    }

    red[tid] = make_float4(ax, ay, az, aw);
    __syncthreads();
    if (tid < 32) {
        float4 r = red[tid];
        #pragma unroll
        for (int k = 1; k < 8; ++k) {
            float4 o = red[tid + 32 * k];
            r.x += o.x; r.y += o.y; r.z += o.z; r.w += o.w;
        }
        ((float4*)aggr)[tid] = r;
    }
    __syncthreads();

    if (tid < 128) {
        const float* xin = (LAYER == 0) ? x0 : x1;
        float xv = xin[(size_t)t * 16384 + (size_t)i * 128 + tid];
        hs[tid] = lrelu(fmaf(cw[0], xv, cw[1] * aggr[tid]));
    }
    __syncthreads();

    int g = tid & 127, half = tid >> 7;
    float acc = 0.f;
    const float* wp = WT + (size_t)(half * 64) * 128 + g;   // WT[f][g], coalesced in g
    const float* hp = hs + half * 64;                       // broadcast
    #pragma unroll 8
    for (int f = 0; f < 64; ++f) acc = fmaf(hp[f], wp[(size_t)f * 128], acc);
    if (half) yred[g] = acc;
    __syncthreads();
    if (!half) {
        float y = acc + yred[g];
        y_out[(size_t)ti * 128 + g] = y;
        atomicAdd(&bnL[g], y);
        atomicAdd(&bnL[128 + g], y * y);
    }
}

extern "C" void kernel_launch(void* const* d_in, const int* in_sizes, int n_in,
                              void* d_out, int out_size, void* d_ws, size_t ws_size,
                              hipStream_t stream) {
    const float* x0    = (const float*)d_in[0];
    const float* E     = (const float*)d_in[1];
    const float* ew    = (const float*)d_in[2];
    const float* eb    = (const float*)d_in[3];
    const float* cw    = (const float*)d_in[4];
    const float* nw    = (const float*)d_in[5];
    const float* gamma = (const float*)d_in[6];
    const float* beta  = (const float*)d_in[7];
    float* out = (float*)d_out;

    float* ws  = (float*)d_ws;
    float* x1  = ws;                 // 262144 floats
    float* yag = ws + 262144;        // 262144 floats (y buffer, reused both layers)
    float* bn  = ws + 524288;        // 512 floats (256 per layer: sum | sumsq)
    float* WT  = ws + 524800;        // 32768 floats (both layers), 16B-aligned

    wprep<<<dim3(64, 2), 256, 0, stream>>>(nw, WT, bn);

    // out[0] = sim_cal(x0)
    sim_k<false><<<dim3(16, 8), 128, 0, stream>>>(x0, nullptr, nullptr, nullptr, out, nullptr);

    // layer 0: fused edge+aggr+node+GEMM+BN-partials, then BN-apply fused into sim_cal
    layer_fused<0><<<2048, 256, 0, stream>>>(x0, x0, E, ew, eb, cw, WT, yag, bn);
    sim_k<true><<<dim3(16, 8), 128, 0, stream>>>(yag, bn, gamma, beta, out + 524288, x1);

    // layer 1 (recompute e0 from original E on the fly)
    layer_fused<1><<<2048, 256, 0, stream>>>(x0, x1, E, ew, eb, cw + 2, WT + 16384, yag, bn + 256);
    sim_k<true><<<dim3(16, 8), 128, 0, stream>>>(yag, bn + 256, gamma + 128, beta + 128,
                                                 out + 1048576, nullptr);
}

// Round 2
// 324.719 us; speedup vs baseline: 1.1846x; 1.1846x over previous
//
#include <hip/hip_runtime.h>

#define T_ 16
#define N_ 128
#define F_ 128

__device__ __forceinline__ float fast_tanh(float x) {
    // tanh(x) = 1 - 2/(exp(2x)+1); v_exp_f32 + native rcp-div. Handles +-inf correctly.
    float e = __expf(2.0f * x);
    return 1.0f - __fdividef(2.0f, e + 1.0f);
}

__device__ __forceinline__ float lrelu(float v) {
    return v >= 0.0f ? v : 0.01f * v;
}

// ---------------- prep: transpose node_w, zero BN accumulators + aggr buffer ----------------
// grid (64, 2) x 256. Poison-safe: everything atomically accumulated later is zeroed here.
__global__ void wprep(const float* __restrict__ W, float* __restrict__ WT,
                      float* __restrict__ bn, float* __restrict__ aggrG) {
    int l = blockIdx.y;
    int idx = blockIdx.x * 256 + threadIdx.x;   // 0..16383
    int g = idx >> 7, f = idx & 127;
    WT[l * 16384 + f * 128 + g] = W[l * 16384 + idx];
    int lin = l * 16384 + idx;                  // 0..32767
    float4 z = make_float4(0.f, 0.f, 0.f, 0.f);
    ((float4*)aggrG)[lin * 2]     = z;          // 262144 floats = 65536 float4
    ((float4*)aggrG)[lin * 2 + 1] = z;
    if (l == 0 && blockIdx.x == 0) {
        bn[threadIdx.x] = 0.0f;          // layer 0 sums
        bn[256 + threadIdx.x] = 0.0f;    // layer 1 sums
    }
}

// ---------------- edge update + partial aggregate ----------------
// grid 4096 (= (t*128+i)*2 + jhalf), block 256 (jl 0..7, fg 0..31).
// Each block: 64 j's (8 iters), accumulates tanh sums, 8-way LDS reduce,
// atomicAdd partial aggr (2 blocks per address -> no contention).
template<int LAYER>
__global__ __launch_bounds__(256) void edge_k(const float* __restrict__ x0,
                                              const float* __restrict__ x1,
                                              const float* __restrict__ E,
                                              const float* __restrict__ ew,
                                              const float* __restrict__ eb,
                                              float* __restrict__ aggrG) {
    __shared__ float4 red[256];
    int b = blockIdx.x;
    int ti = b >> 1, h = b & 1;          // ti = t*128+i
    int t = ti >> 7, i = ti & 127;
    int tid = threadIdx.x, jl = tid >> 5, fg = tid & 31;

    const float4* xt0 = (const float4*)(x0 + (size_t)t * 16384);
    const float4* xt1 = (const float4*)(x1 + (size_t)t * 16384);
    const float4* Ei  = (const float4*)(E + (size_t)ti * 16384);

    float w02 = ew[2], b0 = eb[0];
    float c0 = ew[0] + ew[1], nw01 = -ew[1];
    float c1 = 0.f, nw11 = 0.f, w12 = 0.f, b1 = 0.f;
    if constexpr (LAYER == 1) { c1 = ew[3] + ew[4]; nw11 = -ew[4]; w12 = ew[5]; b1 = eb[1]; }

    float4 xi0 = xt0[i * 32 + fg];
    float4 xi1 = xi0;
    if constexpr (LAYER == 1) xi1 = xt1[i * 32 + fg];

    float4 a = make_float4(0.f, 0.f, 0.f, 0.f);
    int jbase = h * 64;

    if constexpr (LAYER == 0) {
        #pragma unroll 4
        for (int jb = 0; jb < 64; jb += 8) {
            int j = jbase + jb + jl;
            float4 xj0 = xt0[j * 32 + fg];
            float4 ev  = Ei[j * 32 + fg];
            if (j != i) {
                a.x += fast_tanh(fmaf(c0, xi0.x, fmaf(w02, ev.x, fmaf(nw01, xj0.x, b0))));
                a.y += fast_tanh(fmaf(c0, xi0.y, fmaf(w02, ev.y, fmaf(nw01, xj0.y, b0))));
                a.z += fast_tanh(fmaf(c0, xi0.z, fmaf(w02, ev.z, fmaf(nw01, xj0.z, b0))));
                a.w += fast_tanh(fmaf(c0, xi0.w, fmaf(w02, ev.w, fmaf(nw01, xj0.w, b0))));
            }
        }
    } else {
        #pragma unroll 2
        for (int jb = 0; jb < 64; jb += 8) {
            int j = jbase + jb + jl;
            float4 xj0 = xt0[j * 32 + fg];
            float4 xj1 = xt1[j * 32 + fg];
            float4 ev  = Ei[j * 32 + fg];
            if (j != i) {
                float e0x = fast_tanh(fmaf(c0, xi0.x, fmaf(w02, ev.x, fmaf(nw01, xj0.x, b0))));
                float e0y = fast_tanh(fmaf(c0, xi0.y, fmaf(w02, ev.y, fmaf(nw01, xj0.y, b0))));
                float e0z = fast_tanh(fmaf(c0, xi0.z, fmaf(w02, ev.z, fmaf(nw01, xj0.z, b0))));
                float e0w = fast_tanh(fmaf(c0, xi0.w, fmaf(w02, ev.w, fmaf(nw01, xj0.w, b0))));
                a.x += fast_tanh(fmaf(c1, xi1.x, fmaf(w12, e0x, fmaf(nw11, xj1.x, b1))));
                a.y += fast_tanh(fmaf(c1, xi1.y, fmaf(w12, e0y, fmaf(nw11, xj1.y, b1))));
                a.z += fast_tanh(fmaf(c1, xi1.z, fmaf(w12, e0z, fmaf(nw11, xj1.z, b1))));
                a.w += fast_tanh(fmaf(c1, xi1.w, fmaf(w12, e0w, fmaf(nw11, xj1.w, b1))));
            }
        }
    }

    red[tid] = a;
    __syncthreads();
    if (tid < 32) {
        float4 r = red[tid];
        #pragma unroll
        for (int k = 1; k < 8; ++k) {
            float4 o = red[tid + 32 * k];
            r.x += o.x; r.y += o.y; r.z += o.z; r.w += o.w;
        }
        float* ap = aggrG + (size_t)ti * 128 + tid * 4;
        atomicAdd(ap + 0, r.x);
        atomicAdd(ap + 1, r.y);
        atomicAdd(ap + 2, r.z);
        atomicAdd(ap + 3, r.w);
    }
}

// ---------------- node update: h=lrelu(c0*x+c1*aggr); y = h @ W^T; BN partial sums ----------------
// grid (T, 16), block 128 (thread = g), 8 rows/block. CLEAR: re-zero aggrG for next layer.
template<bool CLEAR>
__global__ __launch_bounds__(128) void node_k(const float* __restrict__ x,
                                              float* __restrict__ aggrG,
                                              const float* __restrict__ cw,
                                              const float* __restrict__ WT,
                                              float* __restrict__ y_out,
                                              float* __restrict__ bnL) {
    __shared__ float hs[8][128];
    int t = blockIdx.x, ch = blockIdx.y, g = threadIdx.x;
    float c0 = cw[0], c1 = cw[1];
    size_t base = ((size_t)t * 128 + ch * 8) * 128;
    #pragma unroll
    for (int r = 0; r < 8; ++r) {
        float xv = x[base + r * 128 + g];
        float av = aggrG[base + r * 128 + g];
        hs[r][g] = lrelu(fmaf(c0, xv, c1 * av));
        if (CLEAR) aggrG[base + r * 128 + g] = 0.0f;   // each addr read by exactly this thread
    }
    __syncthreads();
    float acc[8];
    #pragma unroll
    for (int r = 0; r < 8; ++r) acc[r] = 0.0f;
    #pragma unroll 4
    for (int f = 0; f < 128; ++f) {
        float wv = WT[f * 128 + g];
        #pragma unroll
        for (int r = 0; r < 8; ++r) acc[r] = fmaf(hs[r][f], wv, acc[r]);
    }
    float s = 0.0f, ss = 0.0f;
    #pragma unroll
    for (int r = 0; r < 8; ++r) {
        y_out[base + r * 128 + g] = acc[r];
        s += acc[r];
        ss += acc[r] * acc[r];
    }
    atomicAdd(&bnL[g], s);
    atomicAdd(&bnL[128 + g], ss);
}

// ---------------- sim_cal (optionally fused with BN-apply + lrelu + x_next writeback) ----------------
// grid (T, 16), block 128. Each block: full X[t] in LDS, computes 8 n-rows x 128 m-cols.
template<bool BN>
__global__ __launch_bounds__(128) void sim_k(const float* __restrict__ x,
                                             const float* __restrict__ bnS,
                                             const float* __restrict__ gamma,
                                             const float* __restrict__ beta,
                                             float* __restrict__ out,
                                             float* __restrict__ xout) {
    __shared__ float Xs[128][132];   // pad 132: 16B-aligned rows
    __shared__ float nrm[128];
    int t = blockIdx.x, ch = blockIdx.y;
    int m = threadIdx.x;
    const float* xt = x + (size_t)t * (N_ * F_);
    int fg = (m & 31) * 4, ko = m >> 5;

    float4 sc, sh;   // y*sc + sh == (y-mu)*inv*gamma + beta
    if constexpr (BN) {
        float4 s1 = *(const float4*)(bnS + fg);
        float4 s2 = *(const float4*)(bnS + 128 + fg);
        float4 ga = *(const float4*)(gamma + fg);
        float4 be = *(const float4*)(beta + fg);
        const float inv_n = 1.0f / 2048.0f;
        float mx = s1.x * inv_n, my = s1.y * inv_n, mz = s1.z * inv_n, mw = s1.w * inv_n;
        sc.x = rsqrtf(s2.x * inv_n - mx * mx + 1e-5f) * ga.x;
        sc.y = rsqrtf(s2.y * inv_n - my * my + 1e-5f) * ga.y;
        sc.z = rsqrtf(s2.z * inv_n - mz * mz + 1e-5f) * ga.z;
        sc.w = rsqrtf(s2.w * inv_n - mw * mw + 1e-5f) * ga.w;
        sh.x = be.x - mx * sc.x;
        sh.y = be.y - my * sc.y;
        sh.z = be.z - mz * sc.z;
        sh.w = be.w - mw * sc.w;
    }

    bool wout = false;
    if constexpr (BN) wout = (blockIdx.y == 0) && (xout != nullptr);
    for (int kb = 0; kb < 128; kb += 4) {
        int k = kb + ko;
        float4 v = *(const float4*)(xt + k * 128 + fg);
        if constexpr (BN) {
            v.x = lrelu(fmaf(v.x, sc.x, sh.x));
            v.y = lrelu(fmaf(v.y, sc.y, sh.y));
            v.z = lrelu(fmaf(v.z, sc.z, sh.z));
            v.w = lrelu(fmaf(v.w, sc.w, sh.w));
            if (wout) *(float4*)(xout + (size_t)t * 16384 + k * 128 + fg) = v;
        }
        *(float4*)&Xs[k][fg] = v;
    }
    __syncthreads();

    float s = 0.0f;
    #pragma unroll 8
    for (int f = 0; f < 128; f += 4) {
        float4 v = *(float4*)&Xs[m][f];
        s += v.x * v.x + v.y * v.y + v.z * v.z + v.w * v.w;
    }
    nrm[m] = sqrtf(s);
    __syncthreads();

    float acc[8];
    #pragma unroll
    for (int r = 0; r < 8; ++r) acc[r] = 0.0f;

    for (int fc = 0; fc < 128; fc += 32) {
        float xm[32];
        #pragma unroll
        for (int f = 0; f < 32; f += 4) {
            float4 v = *(float4*)&Xs[m][fc + f];
            xm[f] = v.x; xm[f + 1] = v.y; xm[f + 2] = v.z; xm[f + 3] = v.w;
        }
        #pragma unroll
        for (int r = 0; r < 8; ++r) {
            int n = ch * 8 + r;
            #pragma unroll
            for (int f = 0; f < 32; f += 4) {
                float4 v = *(float4*)&Xs[n][fc + f];
                acc[r] = fmaf(xm[f], v.x,
                         fmaf(xm[f + 1], v.y,
                         fmaf(xm[f + 2], v.z,
                         fmaf(xm[f + 3], v.w, acc[r]))));
            }
        }
    }

    float nm = nrm[m];
    size_t ob = (size_t)t * 2 * 16384;
    #pragma unroll
    for (int r = 0; r < 8; ++r) {
        int n = ch * 8 + r;
        float denom = nrm[n] * nm + 1e-6f;
        float sim = __fdividef(acc[r], denom);
        float s0 = fminf(fmaxf(sim, 0.0f), 1.0f);
        float s1 = fminf(fmaxf(1.0f - sim, 0.0f), 1.0f);
        out[ob + (size_t)n * 128 + m] = s0;
        out[ob + 16384 + (size_t)n * 128 + m] = s1;
    }
}

extern "C" void kernel_launch(void* const* d_in, const int* in_sizes, int n_in,
                              void* d_out, int out_size, void* d_ws, size_t ws_size,
                              hipStream_t stream) {
    const float* x0    = (const float*)d_in[0];
    const float* E     = (const float*)d_in[1];
    const float* ew    = (const float*)d_in[2];
    const float* eb    = (const float*)d_in[3];
    const float* cw    = (const float*)d_in[4];
    const float* nw    = (const float*)d_in[5];
    const float* gamma = (const float*)d_in[6];
    const float* beta  = (const float*)d_in[7];
    float* out = (float*)d_out;

    float* ws    = (float*)d_ws;
    float* x1    = ws;                 // 262144 floats
    float* yb    = ws + 262144;        // 262144 floats (y buffer, both layers)
    float* aggrG = ws + 524288;        // 262144 floats (partial aggr, atomically built)
    float* bn    = ws + 786432;        // 512 floats (256 per layer: sum | sumsq)
    float* WT    = ws + 786944;        // 32768 floats (both layers), 16B-aligned

    wprep<<<dim3(64, 2), 256, 0, stream>>>(nw, WT, bn, aggrG);

    // out[0] = sim_cal(x0)
    sim_k<false><<<dim3(16, 16), 128, 0, stream>>>(x0, nullptr, nullptr, nullptr, out, nullptr);

    // layer 0
    edge_k<0><<<4096, 256, 0, stream>>>(x0, x0, E, ew, eb, aggrG);
    node_k<true><<<dim3(16, 16), 128, 0, stream>>>(x0, aggrG, cw, WT, yb, bn);
    sim_k<true><<<dim3(16, 16), 128, 0, stream>>>(yb, bn, gamma, beta, out + 524288, x1);

    // layer 1 (recompute e0 from original E on the fly)
    edge_k<1><<<4096, 256, 0, stream>>>(x0, x1, E, ew, eb, aggrG);
    node_k<false><<<dim3(16, 16), 128, 0, stream>>>(x1, aggrG, cw + 2, WT + 16384, yb, bn + 256);
    sim_k<true><<<dim3(16, 16), 128, 0, stream>>>(yb, bn + 256, gamma + 128, beta + 128,
                                                  out + 1048576, nullptr);
}

// Round 4
// 306.586 us; speedup vs baseline: 1.2547x; 1.0591x over previous
//
#include <hip/hip_runtime.h>

#define T_ 16
#define N_ 128
#define F_ 128

__device__ __forceinline__ float fast_tanh(float x) {
    // tanh(x) = 1 - 2/(exp(2x)+1); v_exp_f32 + native rcp-div. Handles +-inf correctly.
    float e = __expf(2.0f * x);
    return 1.0f - __fdividef(2.0f, e + 1.0f);
}

__device__ __forceinline__ float lrelu(float v) {
    return v >= 0.0f ? v : 0.01f * v;
}

// ---------------- prep: transpose node_w, zero BN accumulators + aggr buffer ----------------
// grid (64, 2) x 256. Poison-safe: everything atomically accumulated later is zeroed here.
__global__ void wprep(const float* __restrict__ W, float* __restrict__ WT,
                      float* __restrict__ bn, float* __restrict__ aggrG) {
    int l = blockIdx.y;
    int idx = blockIdx.x * 256 + threadIdx.x;   // 0..16383
    int g = idx >> 7, f = idx & 127;
    WT[l * 16384 + f * 128 + g] = W[l * 16384 + idx];
    int lin = l * 16384 + idx;                  // 0..32767
    float4 z = make_float4(0.f, 0.f, 0.f, 0.f);
    ((float4*)aggrG)[lin * 2]     = z;          // 262144 floats = 65536 float4
    ((float4*)aggrG)[lin * 2 + 1] = z;
    if (l == 0 && blockIdx.x == 0) {
        bn[threadIdx.x] = 0.0f;          // layer 0 sums
        bn[256 + threadIdx.x] = 0.0f;    // layer 1 sums
    }
}

// ---------------- edge update + partial aggregate ----------------
// grid 4096 (= (t*128+i)*2 + jhalf), block 256 (jl 0..7, fg 0..31).
// Each block: 64 j's. ALL loads for the 64 j's are issued up-front into registers
// (16/24 loads in flight per wave) so HBM/L2 latency pipelines; branchless diag mask.
template<int LAYER>
__global__ __launch_bounds__(256) void edge_k(const float* __restrict__ x0,
                                              const float* __restrict__ x1,
                                              const float* __restrict__ E,
                                              const float* __restrict__ ew,
                                              const float* __restrict__ eb,
                                              float* __restrict__ aggrG) {
    __shared__ float4 red[256];
    int b = blockIdx.x;
    int ti = b >> 1, h = b & 1;          // ti = t*128+i
    int t = ti >> 7, i = ti & 127;
    int tid = threadIdx.x, jl = tid >> 5, fg = tid & 31;

    const float4* xt0 = (const float4*)(x0 + (size_t)t * 16384);
    const float4* xt1 = (const float4*)(x1 + (size_t)t * 16384);
    const float4* Ei  = (const float4*)(E + (size_t)ti * 16384);

    float w02 = ew[2], b0 = eb[0];
    float c0 = ew[0] + ew[1], nw01 = -ew[1];
    float c1 = 0.f, nw11 = 0.f, w12 = 0.f, b1 = 0.f;
    if constexpr (LAYER == 1) { c1 = ew[3] + ew[4]; nw11 = -ew[4]; w12 = ew[5]; b1 = eb[1]; }

    float4 xi0 = xt0[i * 32 + fg];
    float4 xi1 = xi0;
    if constexpr (LAYER == 1) xi1 = xt1[i * 32 + fg];

    float4 a = make_float4(0.f, 0.f, 0.f, 0.f);
    int jbase = h * 64;

    // ---- issue ALL loads first (maximal memory-level parallelism) ----
    float4 xj0[8], ev[8];
    float4 xj1[8];
    #pragma unroll
    for (int k = 0; k < 8; ++k) {
        int j = jbase + k * 8 + jl;
        ev[k]  = Ei[j * 32 + fg];
        xj0[k] = xt0[j * 32 + fg];
        if constexpr (LAYER == 1) xj1[k] = xt1[j * 32 + fg];
    }

    // ---- branchless compute ----
    #pragma unroll
    for (int k = 0; k < 8; ++k) {
        int j = jbase + k * 8 + jl;
        float msk = (j != i) ? 1.0f : 0.0f;
        if constexpr (LAYER == 0) {
            a.x += msk * fast_tanh(fmaf(c0, xi0.x, fmaf(w02, ev[k].x, fmaf(nw01, xj0[k].x, b0))));
            a.y += msk * fast_tanh(fmaf(c0, xi0.y, fmaf(w02, ev[k].y, fmaf(nw01, xj0[k].y, b0))));
            a.z += msk * fast_tanh(fmaf(c0, xi0.z, fmaf(w02, ev[k].z, fmaf(nw01, xj0[k].z, b0))));
            a.w += msk * fast_tanh(fmaf(c0, xi0.w, fmaf(w02, ev[k].w, fmaf(nw01, xj0[k].w, b0))));
        } else {
            float e0x = fast_tanh(fmaf(c0, xi0.x, fmaf(w02, ev[k].x, fmaf(nw01, xj0[k].x, b0))));
            float e0y = fast_tanh(fmaf(c0, xi0.y, fmaf(w02, ev[k].y, fmaf(nw01, xj0[k].y, b0))));
            float e0z = fast_tanh(fmaf(c0, xi0.z, fmaf(w02, ev[k].z, fmaf(nw01, xj0[k].z, b0))));
            float e0w = fast_tanh(fmaf(c0, xi0.w, fmaf(w02, ev[k].w, fmaf(nw01, xj0[k].w, b0))));
            a.x += msk * fast_tanh(fmaf(c1, xi1.x, fmaf(w12, e0x, fmaf(nw11, xj1[k].x, b1))));
            a.y += msk * fast_tanh(fmaf(c1, xi1.y, fmaf(w12, e0y, fmaf(nw11, xj1[k].y, b1))));
            a.z += msk * fast_tanh(fmaf(c1, xi1.z, fmaf(w12, e0z, fmaf(nw11, xj1[k].z, b1))));
            a.w += msk * fast_tanh(fmaf(c1, xi1.w, fmaf(w12, e0w, fmaf(nw11, xj1[k].w, b1))));
        }
    }

    red[tid] = a;
    __syncthreads();
    if (tid < 32) {
        float4 r = red[tid];
        #pragma unroll
        for (int k = 1; k < 8; ++k) {
            float4 o = red[tid + 32 * k];
            r.x += o.x; r.y += o.y; r.z += o.z; r.w += o.w;
        }
        float* ap = aggrG + (size_t)ti * 128 + tid * 4;
        atomicAdd(ap + 0, r.x);
        atomicAdd(ap + 1, r.y);
        atomicAdd(ap + 2, r.z);
        atomicAdd(ap + 3, r.w);
    }
}

// ---------------- node update: h=lrelu(c0*x+c1*aggr); y = h @ W^T; BN partial sums ----------------
// grid (T, 16), block 128 (thread = g), 8 rows/block. CLEAR: re-zero aggrG for next layer.
template<bool CLEAR>
__global__ __launch_bounds__(128) void node_k(const float* __restrict__ x,
                                              float* __restrict__ aggrG,
                                              const float* __restrict__ cw,
                                              const float* __restrict__ WT,
                                              float* __restrict__ y_out,
                                              float* __restrict__ bnL) {
    __shared__ float hs[8][128];
    int t = blockIdx.x, ch = blockIdx.y, g = threadIdx.x;
    float c0 = cw[0], c1 = cw[1];
    size_t base = ((size_t)t * 128 + ch * 8) * 128;
    #pragma unroll
    for (int r = 0; r < 8; ++r) {
        float xv = x[base + r * 128 + g];
        float av = aggrG[base + r * 128 + g];
        hs[r][g] = lrelu(fmaf(c0, xv, c1 * av));
        if (CLEAR) aggrG[base + r * 128 + g] = 0.0f;   // each addr read by exactly this thread
    }
    __syncthreads();
    float acc[8];
    #pragma unroll
    for (int r = 0; r < 8; ++r) acc[r] = 0.0f;
    #pragma unroll 4
    for (int f = 0; f < 128; ++f) {
        float wv = WT[f * 128 + g];
        #pragma unroll
        for (int r = 0; r < 8; ++r) acc[r] = fmaf(hs[r][f], wv, acc[r]);
    }
    float s = 0.0f, ss = 0.0f;
    #pragma unroll
    for (int r = 0; r < 8; ++r) {
        y_out[base + r * 128 + g] = acc[r];
        s += acc[r];
        ss += acc[r] * acc[r];
    }
    atomicAdd(&bnL[g], s);
    atomicAdd(&bnL[128 + g], ss);
}

// ---------------- sim_cal (optionally fused with BN-apply + lrelu + x_next writeback) ----------------
// grid (T, 16), block 256 (m = tid&127, row-half = tid>>7). Full X[t] in LDS;
// block computes 8 n-rows x 128 m-cols, split 4 rows per thread-half (4 waves/CU).
template<bool BN>
__global__ __launch_bounds__(256) void sim_k(const float* __restrict__ x,
                                             const float* __restrict__ bnS,
                                             const float* __restrict__ gamma,
                                             const float* __restrict__ beta,
                                             float* __restrict__ out,
                                             float* __restrict__ xout) {
    __shared__ float Xs[128][132];   // pad 132: 16B-aligned rows
    __shared__ float nrm[128];
    int t = blockIdx.x, ch = blockIdx.y;
    int tid = threadIdx.x;
    int m = tid & 127, rh = tid >> 7;
    const float* xt = x + (size_t)t * (N_ * F_);
    int fg = (tid & 31) * 4, ko = tid >> 5;   // cooperative-load mapping (8 k-rows/iter)

    float4 sc, sh;   // y*sc + sh == (y-mu)*inv*gamma + beta
    if constexpr (BN) {
        float4 s1 = *(const float4*)(bnS + fg);
        float4 s2 = *(const float4*)(bnS + 128 + fg);
        float4 ga = *(const float4*)(gamma + fg);
        float4 be = *(const float4*)(beta + fg);
        const float inv_n = 1.0f / 2048.0f;
        float mx = s1.x * inv_n, my = s1.y * inv_n, mz = s1.z * inv_n, mw = s1.w * inv_n;
        sc.x = rsqrtf(s2.x * inv_n - mx * mx + 1e-5f) * ga.x;
        sc.y = rsqrtf(s2.y * inv_n - my * my + 1e-5f) * ga.y;
        sc.z = rsqrtf(s2.z * inv_n - mz * mz + 1e-5f) * ga.z;
        sc.w = rsqrtf(s2.w * inv_n - mw * mw + 1e-5f) * ga.w;
        sh.x = be.x - mx * sc.x;
        sh.y = be.y - my * sc.y;
        sh.z = be.z - mz * sc.z;
        sh.w = be.w - mw * sc.w;
    }

    bool wout = false;
    if constexpr (BN) wout = (blockIdx.y == 0) && (xout != nullptr);
    for (int kb = 0; kb < 128; kb += 8) {
        int k = kb + ko;
        float4 v = *(const float4*)(xt + k * 128 + fg);
        if constexpr (BN) {
            v.x = lrelu(fmaf(v.x, sc.x, sh.x));
            v.y = lrelu(fmaf(v.y, sc.y, sh.y));
            v.z = lrelu(fmaf(v.z, sc.z, sh.z));
            v.w = lrelu(fmaf(v.w, sc.w, sh.w));
            if (wout) *(float4*)(xout + (size_t)t * 16384 + k * 128 + fg) = v;
        }
        *(float4*)&Xs[k][fg] = v;
    }
    __syncthreads();

    if (tid < 128) {
        float s = 0.0f;
        #pragma unroll 8
        for (int f = 0; f < 128; f += 4) {
            float4 v = *(float4*)&Xs[m][f];
            s += v.x * v.x + v.y * v.y + v.z * v.z + v.w * v.w;
        }
        nrm[m] = sqrtf(s);
    }
    __syncthreads();

    float acc[4];
    #pragma unroll
    for (int r = 0; r < 4; ++r) acc[r] = 0.0f;

    for (int fc = 0; fc < 128; fc += 32) {
        float xm[32];
        #pragma unroll
        for (int f = 0; f < 32; f += 4) {
            float4 v = *(float4*)&Xs[m][fc + f];
            xm[f] = v.x; xm[f + 1] = v.y; xm[f + 2] = v.z; xm[f + 3] = v.w;
        }
        #pragma unroll
        for (int r = 0; r < 4; ++r) {
            int n = ch * 8 + rh * 4 + r;
            #pragma unroll
            for (int f = 0; f < 32; f += 4) {
                float4 v = *(float4*)&Xs[n][fc + f];
                acc[r] = fmaf(xm[f], v.x,
                         fmaf(xm[f + 1], v.y,
                         fmaf(xm[f + 2], v.z,
                         fmaf(xm[f + 3], v.w, acc[r]))));
            }
        }
    }

    float nm = nrm[m];
    size_t ob = (size_t)t * 2 * 16384;
    #pragma unroll
    for (int r = 0; r < 4; ++r) {
        int n = ch * 8 + rh * 4 + r;
        float denom = nrm[n] * nm + 1e-6f;
        float sim = __fdividef(acc[r], denom);
        float s0 = fminf(fmaxf(sim, 0.0f), 1.0f);
        float s1 = fminf(fmaxf(1.0f - sim, 0.0f), 1.0f);
        out[ob + (size_t)n * 128 + m] = s0;
        out[ob + 16384 + (size_t)n * 128 + m] = s1;
    }
}

extern "C" void kernel_launch(void* const* d_in, const int* in_sizes, int n_in,
                              void* d_out, int out_size, void* d_ws, size_t ws_size,
                              hipStream_t stream) {
    const float* x0    = (const float*)d_in[0];
    const float* E     = (const float*)d_in[1];
    const float* ew    = (const float*)d_in[2];
    const float* eb    = (const float*)d_in[3];
    const float* cw    = (const float*)d_in[4];
    const float* nw    = (const float*)d_in[5];
    const float* gamma = (const float*)d_in[6];
    const float* beta  = (const float*)d_in[7];
    float* out = (float*)d_out;

    float* ws    = (float*)d_ws;
    float* x1    = ws;                 // 262144 floats
    float* yb    = ws + 262144;        // 262144 floats (y buffer, both layers)
    float* aggrG = ws + 524288;        // 262144 floats (partial aggr, atomically built)
    float* bn    = ws + 786432;        // 512 floats (256 per layer: sum | sumsq)
    float* WT    = ws + 786944;        // 32768 floats (both layers), 16B-aligned

    wprep<<<dim3(64, 2), 256, 0, stream>>>(nw, WT, bn, aggrG);

    // out[0] = sim_cal(x0)
    sim_k<false><<<dim3(16, 16), 256, 0, stream>>>(x0, nullptr, nullptr, nullptr, out, nullptr);

    // layer 0
    edge_k<0><<<4096, 256, 0, stream>>>(x0, x0, E, ew, eb, aggrG);
    node_k<true><<<dim3(16, 16), 128, 0, stream>>>(x0, aggrG, cw, WT, yb, bn);
    sim_k<true><<<dim3(16, 16), 256, 0, stream>>>(yb, bn, gamma, beta, out + 524288, x1);

    // layer 1 (recompute e0 from original E on the fly)
    edge_k<1><<<4096, 256, 0, stream>>>(x0, x1, E, ew, eb, aggrG);
    node_k<false><<<dim3(16, 16), 128, 0, stream>>>(x1, aggrG, cw + 2, WT + 16384, yb, bn + 256);
    sim_k<true><<<dim3(16, 16), 256, 0, stream>>>(yb, bn + 256, gamma + 128, beta + 128,
                                                  out + 1048576, nullptr);
}

// Round 5
// 303.058 us; speedup vs baseline: 1.2693x; 1.0116x over previous
//
#include <hip/hip_runtime.h>

#define T_ 16
#define N_ 128
#define F_ 128

__device__ __forceinline__ float fast_tanh(float x) {
    // tanh(x) = 1 - 2/(exp(2x)+1); v_exp_f32 + native rcp-div. Handles +-inf correctly.
    float e = __expf(2.0f * x);
    return 1.0f - __fdividef(2.0f, e + 1.0f);
}

__device__ __forceinline__ float lrelu(float v) {
    return v >= 0.0f ? v : 0.01f * v;
}

// ---------------- prep: transpose node_w + zero BN accumulators ----------------
// grid (64, 2) x 256. bn is atomically accumulated later -> must be zeroed (poison-safe).
__global__ void wprep(const float* __restrict__ W, float* __restrict__ WT,
                      float* __restrict__ bn) {
    int l = blockIdx.y;
    int idx = blockIdx.x * 256 + threadIdx.x;   // 0..16383
    int g = idx >> 7, f = idx & 127;
    WT[l * 16384 + f * 128 + g] = W[l * 16384 + idx];
    if (l == 0 && blockIdx.x == 0) {
        bn[threadIdx.x] = 0.0f;          // layer 0 sums
        bn[256 + threadIdx.x] = 0.0f;    // layer 1 sums
    }
}

// ---------------- edge update + partial aggregate ----------------
// grid 8192 (= (t*128+i)*4 + quarter), block 256 (jl 0..7, fg 0..31).
// Each block: 32 j's (4 x 8). All 8/12 float4 loads issued up-front (reg batch),
// branchless diag mask, 8-way LDS reduce, NON-atomic write to private quarter slot.
// aggrP fully written by construction -> no pre-zero needed (poison-safe).
template<int LAYER>
__global__ __launch_bounds__(256) void edge_k(const float* __restrict__ x0,
                                              const float* __restrict__ x1,
                                              const float* __restrict__ E,
                                              const float* __restrict__ ew,
                                              const float* __restrict__ eb,
                                              float* __restrict__ aggrP) {
    __shared__ float4 red[256];
    int b = blockIdx.x;
    int ti = b >> 2, q = b & 3;          // ti = t*128+i, q = j-quarter
    int t = ti >> 7, i = ti & 127;
    int tid = threadIdx.x, jl = tid >> 5, fg = tid & 31;

    const float4* xt0 = (const float4*)(x0 + (size_t)t * 16384);
    const float4* xt1 = (const float4*)(x1 + (size_t)t * 16384);
    const float4* Ei  = (const float4*)(E + (size_t)ti * 16384);

    float w02 = ew[2], b0 = eb[0];
    float c0 = ew[0] + ew[1], nw01 = -ew[1];
    float c1 = 0.f, nw11 = 0.f, w12 = 0.f, b1 = 0.f;
    if constexpr (LAYER == 1) { c1 = ew[3] + ew[4]; nw11 = -ew[4]; w12 = ew[5]; b1 = eb[1]; }

    float4 xi0 = xt0[i * 32 + fg];
    float4 xi1 = xi0;
    if constexpr (LAYER == 1) xi1 = xt1[i * 32 + fg];

    float4 a = make_float4(0.f, 0.f, 0.f, 0.f);
    int jbase = q * 32;

    // ---- issue all loads first (8 or 12 float4 in flight per thread) ----
    float4 xj0[4], ev[4], xj1[4];
    #pragma unroll
    for (int k = 0; k < 4; ++k) {
        int j = jbase + k * 8 + jl;
        ev[k]  = Ei[j * 32 + fg];
        xj0[k] = xt0[j * 32 + fg];
        if constexpr (LAYER == 1) xj1[k] = xt1[j * 32 + fg];
    }

    // ---- branchless compute ----
    #pragma unroll
    for (int k = 0; k < 4; ++k) {
        int j = jbase + k * 8 + jl;
        float msk = (j != i) ? 1.0f : 0.0f;
        if constexpr (LAYER == 0) {
            a.x += msk * fast_tanh(fmaf(c0, xi0.x, fmaf(w02, ev[k].x, fmaf(nw01, xj0[k].x, b0))));
            a.y += msk * fast_tanh(fmaf(c0, xi0.y, fmaf(w02, ev[k].y, fmaf(nw01, xj0[k].y, b0))));
            a.z += msk * fast_tanh(fmaf(c0, xi0.z, fmaf(w02, ev[k].z, fmaf(nw01, xj0[k].z, b0))));
            a.w += msk * fast_tanh(fmaf(c0, xi0.w, fmaf(w02, ev[k].w, fmaf(nw01, xj0[k].w, b0))));
        } else {
            float e0x = fast_tanh(fmaf(c0, xi0.x, fmaf(w02, ev[k].x, fmaf(nw01, xj0[k].x, b0))));
            float e0y = fast_tanh(fmaf(c0, xi0.y, fmaf(w02, ev[k].y, fmaf(nw01, xj0[k].y, b0))));
            float e0z = fast_tanh(fmaf(c0, xi0.z, fmaf(w02, ev[k].z, fmaf(nw01, xj0[k].z, b0))));
            float e0w = fast_tanh(fmaf(c0, xi0.w, fmaf(w02, ev[k].w, fmaf(nw01, xj0[k].w, b0))));
            a.x += msk * fast_tanh(fmaf(c1, xi1.x, fmaf(w12, e0x, fmaf(nw11, xj1[k].x, b1))));
            a.y += msk * fast_tanh(fmaf(c1, xi1.y, fmaf(w12, e0y, fmaf(nw11, xj1[k].y, b1))));
            a.z += msk * fast_tanh(fmaf(c1, xi1.z, fmaf(w12, e0z, fmaf(nw11, xj1[k].z, b1))));
            a.w += msk * fast_tanh(fmaf(c1, xi1.w, fmaf(w12, e0w, fmaf(nw11, xj1[k].w, b1))));
        }
    }

    red[tid] = a;
    __syncthreads();
    if (tid < 32) {
        float4 r = red[tid];
        #pragma unroll
        for (int k = 1; k < 8; ++k) {
            float4 o = red[tid + 32 * k];
            r.x += o.x; r.y += o.y; r.z += o.z; r.w += o.w;
        }
        ((float4*)(aggrP + (size_t)q * 262144))[ti * 32 + tid] = r;
    }
}

// ---------------- node update: h=lrelu(c0*x+c1*sum(aggrP)); y = h @ W^T; BN partials ----------------
// grid (T, 16), block 128 (thread = g), 8 rows/block.
__global__ __launch_bounds__(128) void node_k(const float* __restrict__ x,
                                              const float* __restrict__ aggrP,
                                              const float* __restrict__ cw,
                                              const float* __restrict__ WT,
                                              float* __restrict__ y_out,
                                              float* __restrict__ bnL) {
    __shared__ float hs[8][128];
    int t = blockIdx.x, ch = blockIdx.y, g = threadIdx.x;
    float c0 = cw[0], c1 = cw[1];
    size_t base = ((size_t)t * 128 + ch * 8) * 128;
    #pragma unroll
    for (int r = 0; r < 8; ++r) {
        float xv = x[base + r * 128 + g];
        float av = aggrP[base + r * 128 + g]
                 + aggrP[262144 + base + r * 128 + g]
                 + aggrP[524288 + base + r * 128 + g]
                 + aggrP[786432 + base + r * 128 + g];
        hs[r][g] = lrelu(fmaf(c0, xv, c1 * av));
    }
    __syncthreads();
    float acc[8];
    #pragma unroll
    for (int r = 0; r < 8; ++r) acc[r] = 0.0f;
    #pragma unroll 4
    for (int f = 0; f < 128; ++f) {
        float wv = WT[f * 128 + g];
        #pragma unroll
        for (int r = 0; r < 8; ++r) acc[r] = fmaf(hs[r][f], wv, acc[r]);
    }
    float s = 0.0f, ss = 0.0f;
    #pragma unroll
    for (int r = 0; r < 8; ++r) {
        y_out[base + r * 128 + g] = acc[r];
        s += acc[r];
        ss += acc[r] * acc[r];
    }
    atomicAdd(&bnL[g], s);
    atomicAdd(&bnL[128 + g], ss);
}

// ---------------- sim_cal (optionally fused with BN-apply + lrelu + x_next writeback) ----------------
// grid (T, 16), block 256 (m = tid&127, row-half = tid>>7). Full X[t] in LDS;
// block computes 8 n-rows x 128 m-cols, split 4 rows per thread-half.
template<bool BN>
__global__ __launch_bounds__(256) void sim_k(const float* __restrict__ x,
                                             const float* __restrict__ bnS,
                                             const float* __restrict__ gamma,
                                             const float* __restrict__ beta,
                                             float* __restrict__ out,
                                             float* __restrict__ xout) {
    __shared__ float Xs[128][132];   // pad 132: 16B-aligned rows
    __shared__ float nrm[128];
    int t = blockIdx.x, ch = blockIdx.y;
    int tid = threadIdx.x;
    int m = tid & 127, rh = tid >> 7;
    const float* xt = x + (size_t)t * (N_ * F_);
    int fg = (tid & 31) * 4, ko = tid >> 5;   // cooperative-load mapping (8 k-rows/iter)

    float4 sc, sh;   // y*sc + sh == (y-mu)*inv*gamma + beta
    if constexpr (BN) {
        float4 s1 = *(const float4*)(bnS + fg);
        float4 s2 = *(const float4*)(bnS + 128 + fg);
        float4 ga = *(const float4*)(gamma + fg);
        float4 be = *(const float4*)(beta + fg);
        const float inv_n = 1.0f / 2048.0f;
        float mx = s1.x * inv_n, my = s1.y * inv_n, mz = s1.z * inv_n, mw = s1.w * inv_n;
        sc.x = rsqrtf(s2.x * inv_n - mx * mx + 1e-5f) * ga.x;
        sc.y = rsqrtf(s2.y * inv_n - my * my + 1e-5f) * ga.y;
        sc.z = rsqrtf(s2.z * inv_n - mz * mz + 1e-5f) * ga.z;
        sc.w = rsqrtf(s2.w * inv_n - mw * mw + 1e-5f) * ga.w;
        sh.x = be.x - mx * sc.x;
        sh.y = be.y - my * sc.y;
        sh.z = be.z - mz * sc.z;
        sh.w = be.w - mw * sc.w;
    }

    bool wout = false;
    if constexpr (BN) wout = (blockIdx.y == 0) && (xout != nullptr);
    for (int kb = 0; kb < 128; kb += 8) {
        int k = kb + ko;
        float4 v = *(const float4*)(xt + k * 128 + fg);
        if constexpr (BN) {
            v.x = lrelu(fmaf(v.x, sc.x, sh.x));
            v.y = lrelu(fmaf(v.y, sc.y, sh.y));
            v.z = lrelu(fmaf(v.z, sc.z, sh.z));
            v.w = lrelu(fmaf(v.w, sc.w, sh.w));
            if (wout) *(float4*)(xout + (size_t)t * 16384 + k * 128 + fg) = v;
        }
        *(float4*)&Xs[k][fg] = v;
    }
    __syncthreads();

    if (tid < 128) {
        float s = 0.0f;
        #pragma unroll 8
        for (int f = 0; f < 128; f += 4) {
            float4 v = *(float4*)&Xs[m][f];
            s += v.x * v.x + v.y * v.y + v.z * v.z + v.w * v.w;
        }
        nrm[m] = sqrtf(s);
    }
    __syncthreads();

    float acc[4];
    #pragma unroll
    for (int r = 0; r < 4; ++r) acc[r] = 0.0f;

    for (int fc = 0; fc < 128; fc += 32) {
        float xm[32];
        #pragma unroll
        for (int f = 0; f < 32; f += 4) {
            float4 v = *(float4*)&Xs[m][fc + f];
            xm[f] = v.x; xm[f + 1] = v.y; xm[f + 2] = v.z; xm[f + 3] = v.w;
        }
        #pragma unroll
        for (int r = 0; r < 4; ++r) {
            int n = ch * 8 + rh * 4 + r;
            #pragma unroll
            for (int f = 0; f < 32; f += 4) {
                float4 v = *(float4*)&Xs[n][fc + f];
                acc[r] = fmaf(xm[f], v.x,
                         fmaf(xm[f + 1], v.y,
                         fmaf(xm[f + 2], v.z,
                         fmaf(xm[f + 3], v.w, acc[r]))));
            }
        }
    }

    float nm = nrm[m];
    size_t ob = (size_t)t * 2 * 16384;
    #pragma unroll
    for (int r = 0; r < 4; ++r) {
        int n = ch * 8 + rh * 4 + r;
        float denom = nrm[n] * nm + 1e-6f;
        float sim = __fdividef(acc[r], denom);
        float s0 = fminf(fmaxf(sim, 0.0f), 1.0f);
        float s1 = fminf(fmaxf(1.0f - sim, 0.0f), 1.0f);
        out[ob + (size_t)n * 128 + m] = s0;
        out[ob + 16384 + (size_t)n * 128 + m] = s1;
    }
}

extern "C" void kernel_launch(void* const* d_in, const int* in_sizes, int n_in,
                              void* d_out, int out_size, void* d_ws, size_t ws_size,
                              hipStream_t stream) {
    const float* x0    = (const float*)d_in[0];
    const float* E     = (const float*)d_in[1];
    const float* ew    = (const float*)d_in[2];
    const float* eb    = (const float*)d_in[3];
    const float* cw    = (const float*)d_in[4];
    const float* nw    = (const float*)d_in[5];
    const float* gamma = (const float*)d_in[6];
    const float* beta  = (const float*)d_in[7];
    float* out = (float*)d_out;

    float* ws    = (float*)d_ws;
    float* x1    = ws;                 // 262144 floats
    float* yb    = ws + 262144;        // 262144 floats (y buffer, both layers)
    float* aggrP = ws + 524288;        // 4 x 262144 floats (quarter partials, non-atomic)
    float* bn    = ws + 1572864;       // 512 floats (256 per layer: sum | sumsq)
    float* WT    = ws + 1573376;       // 32768 floats (both layers), 16B-aligned

    wprep<<<dim3(64, 2), 256, 0, stream>>>(nw, WT, bn);

    // out[0] = sim_cal(x0)
    sim_k<false><<<dim3(16, 16), 256, 0, stream>>>(x0, nullptr, nullptr, nullptr, out, nullptr);

    // layer 0
    edge_k<0><<<8192, 256, 0, stream>>>(x0, x0, E, ew, eb, aggrP);
    node_k<<<dim3(16, 16), 128, 0, stream>>>(x0, aggrP, cw, WT, yb, bn);
    sim_k<true><<<dim3(16, 16), 256, 0, stream>>>(yb, bn, gamma, beta, out + 524288, x1);

    // layer 1 (recompute e0 from original E on the fly)
    edge_k<1><<<8192, 256, 0, stream>>>(x0, x1, E, ew, eb, aggrP);
    node_k<<<dim3(16, 16), 128, 0, stream>>>(x1, aggrP, cw + 2, WT + 16384, yb, bn + 256);
    sim_k<true><<<dim3(16, 16), 256, 0, stream>>>(yb, bn + 256, gamma + 128, beta + 128,
                                                  out + 1048576, nullptr);
}